// Round 15
// baseline (236.118 us; speedup 1.0000x reference)
//
#include <hip/hip_runtime.h>
#include <hip/hip_bf16.h>
#include <math.h>

#define NN 65536
#define NE 1048576
#define DEG_SCALE 33554432.0f  // 2^25

__device__ inline float4 f4fma(float s, float4 v, float4 a) {
    a.x = fmaf(s, v.x, a.x);
    a.y = fmaf(s, v.y, a.y);
    a.z = fmaf(s, v.z, a.z);
    a.w = fmaf(s, v.w, a.w);
    return a;
}

__device__ inline unsigned pack2bf(float a, float b) {
    __hip_bfloat16 ha = __float2bfloat16(a), hb = __float2bfloat16(b);
    return (unsigned)*reinterpret_cast<unsigned short*>(&ha) |
           ((unsigned)*reinterpret_cast<unsigned short*>(&hb) << 16);
}

__device__ inline unsigned short bf16bits(float a) {
    __hip_bfloat16 h = __float2bfloat16(a);
    return *reinterpret_cast<unsigned short*>(&h);
}

__device__ inline void bfx8(uint4 v, float* f) {  // 8 bf16 -> 8 fp32
    f[0] = __uint_as_float(v.x << 16);
    f[1] = __uint_as_float(v.x & 0xffff0000u);
    f[2] = __uint_as_float(v.y << 16);
    f[3] = __uint_as_float(v.y & 0xffff0000u);
    f[4] = __uint_as_float(v.z << 16);
    f[5] = __uint_as_float(v.z & 0xffff0000u);
    f[6] = __uint_as_float(v.w << 16);
    f[7] = __uint_as_float(v.w & 0xffff0000u);
}

// mm body, fp32 A input: C[64x64](bf16) = A[64 x K](fp32) @ W[K x 64](fp32)
template <int K>
__device__ void mm64_body_bf(const float* __restrict__ A, const float* __restrict__ W,
                             unsigned short* __restrict__ Cb, int node0, int tid) {
    __shared__ float As[64 * 68];
    __shared__ float Ws[64 * 64];
    const int tx = tid & 15;
    const int ty = tid >> 4;
    float4 acc[4];
#pragma unroll
    for (int m = 0; m < 4; ++m) acc[m] = make_float4(0.f, 0.f, 0.f, 0.f);

    for (int kc = 0; kc < K; kc += 64) {
#pragma unroll
        for (int p = 0; p < 4; ++p) {
            int idx = tid + p * 256;
            int r = idx >> 4, c4 = idx & 15;
            float4 v = *reinterpret_cast<const float4*>(A + (size_t)(node0 + r) * K + kc + c4 * 4);
            *reinterpret_cast<float4*>(&As[r * 68 + c4 * 4]) = v;
        }
#pragma unroll
        for (int p = 0; p < 4; ++p) {
            int idx = tid + p * 256;
            int r = idx >> 4, c4 = idx & 15;
            float4 v = *reinterpret_cast<const float4*>(W + (size_t)(kc + r) * 64 + c4 * 4);
            *reinterpret_cast<float4*>(&Ws[r * 64 + c4 * 4]) = v;
        }
        __syncthreads();
#pragma unroll 16
        for (int k = 0; k < 64; ++k) {
            float4 w = *reinterpret_cast<const float4*>(&Ws[k * 64 + tx * 4]);
            float a0 = As[(ty * 4 + 0) * 68 + k];
            float a1 = As[(ty * 4 + 1) * 68 + k];
            float a2 = As[(ty * 4 + 2) * 68 + k];
            float a3 = As[(ty * 4 + 3) * 68 + k];
            acc[0] = f4fma(a0, w, acc[0]);
            acc[1] = f4fma(a1, w, acc[1]);
            acc[2] = f4fma(a2, w, acc[2]);
            acc[3] = f4fma(a3, w, acc[3]);
        }
        __syncthreads();
    }
#pragma unroll
    for (int m = 0; m < 4; ++m) {
        uint2 pk;
        pk.x = pack2bf(acc[m].x, acc[m].y);
        pk.y = pack2bf(acc[m].z, acc[m].w);
        *reinterpret_cast<uint2*>(Cb + (size_t)(node0 + ty * 4 + m) * 64 + tx * 4) = pk;
    }
}

// ---------------- setup kernels ----------------

// pure atomic pass: one 64-bit atomic per edge; rank = returned old count.
__global__ void __launch_bounds__(256) deg_count(const int* __restrict__ col,
                                                 const float* __restrict__ ew,
                                                 unsigned long long* __restrict__ cntdeg,
                                                 int* __restrict__ rank) {
    int e = blockIdx.x * 256 + threadIdx.x;
    if (e < NE) {
        int c = col[e];
        unsigned long long p =
            (1ull << 32) | (unsigned long long)__float2uint_rn(ew[e] * DEG_SCALE);
        unsigned long long old = atomicAdd(&cntdeg[c], p);
        rank[e] = (int)(old >> 32);
    }
}

// phase 1: per-block (256 nodes) exclusive scan of counts; emit block total + dinv.
__global__ void __launch_bounds__(256) scan1(const unsigned long long* __restrict__ cntdeg,
                                             int* __restrict__ row_ptr,
                                             int* __restrict__ blocksum,
                                             float* __restrict__ dinv) {
    __shared__ int ls[256];
    const int t = threadIdx.x;
    const int i = blockIdx.x * 256 + t;
    unsigned long long v = cntdeg[i];
    const int c = (int)(v >> 32);
    float deg = (float)(unsigned)(v & 0xffffffffull) * (1.0f / DEG_SCALE) + 1.0f;
    dinv[i] = 1.0f / sqrtf(deg);
    ls[t] = c;
    __syncthreads();
#pragma unroll
    for (int off = 1; off < 256; off <<= 1) {
        int u = (t >= off) ? ls[t - off] : 0;
        __syncthreads();
        ls[t] += u;
        __syncthreads();
    }
    row_ptr[i] = ls[t] - c;  // exclusive
    if (t == 255) blocksum[blockIdx.x] = ls[255];
}

__global__ void __launch_bounds__(256) scan2(const int* __restrict__ blocksum,
                                             int* __restrict__ blockbase,
                                             int* __restrict__ row_ptr) {
    __shared__ int ls[256];
    const int t = threadIdx.x;
    const int c = blocksum[t];
    ls[t] = c;
    __syncthreads();
#pragma unroll
    for (int off = 1; off < 256; off <<= 1) {
        int u = (t >= off) ? ls[t - off] : 0;
        __syncthreads();
        ls[t] += u;
        __syncthreads();
    }
    blockbase[t] = ls[t] - c;
    if (t == 255) row_ptr[NN] = ls[255];
}

__global__ void __launch_bounds__(256) scan3(int* __restrict__ row_ptr,
                                             const int* __restrict__ blockbase) {
    const int i = blockIdx.x * 256 + threadIdx.x;
    row_ptr[i] += blockbase[blockIdx.x];
}

// atomic-free CSR fill (4-byte records) MERGED with layer-1 mm (x@W1 -> Tb, bf16).
// fill blocks are scatter-latency-bound (VALU ~1%) -> mm blocks hide under them.
__global__ void __launch_bounds__(256) fill_mm(const int* __restrict__ row,
                                               const int* __restrict__ col,
                                               const float* __restrict__ ew,
                                               const float* __restrict__ dinv,
                                               const int* __restrict__ row_ptr,
                                               const int* __restrict__ rank,
                                               unsigned* __restrict__ epack,
                                               const float* __restrict__ x,
                                               const float* __restrict__ W1,
                                               unsigned short* __restrict__ Tb) {
    const int bid = blockIdx.x;
    const int tid = threadIdx.x;
    if (bid % 5 == 0) {
        mm64_body_bf<128>(x, W1, Tb, (bid / 5) * 64, tid);
    } else {
        int e = (bid - bid / 5 - 1) * 256 + tid;
        if (e < NE) {
            int c = col[e], r = row[e];
            int idx = row_ptr[c] + rank[e];
            float nrm = dinv[r] * ew[e] * dinv[c];
            epack[idx] = ((unsigned)r << 16) | (unsigned)bf16bits(nrm);
        }
    }
}

// ---------------- fused layer kernels ----------------

// gather phase: 8 lanes per node, 8-wide clamped-predicated loop, fp32 acc.
// edge record: src = p>>16, nrm = as_float(p<<16).
__device__ inline void gather_node(const uint4* __restrict__ T4,
                                   const float* __restrict__ bias,
                                   const float* __restrict__ dinv,
                                   const int* __restrict__ row_ptr,
                                   const unsigned* __restrict__ epack,
                                   int node, int l, float* acc) {
    const float dv = dinv[node];
    {
        float ts[8];
        bfx8(T4[(size_t)node * 8 + l], ts);
        float4 bA = *reinterpret_cast<const float4*>(bias + l * 8);
        float4 bB = *reinterpret_cast<const float4*>(bias + l * 8 + 4);
        acc[0] = bA.x + dv * dv * ts[0];
        acc[1] = bA.y + dv * dv * ts[1];
        acc[2] = bA.z + dv * dv * ts[2];
        acc[3] = bA.w + dv * dv * ts[3];
        acc[4] = bB.x + dv * dv * ts[4];
        acc[5] = bB.y + dv * dv * ts[5];
        acc[6] = bB.z + dv * dv * ts[6];
        acc[7] = bB.w + dv * dv * ts[7];
    }
    const int s = row_ptr[node];
    const int e = row_ptr[node + 1];
    for (int i0 = s; i0 < e; i0 += 8) {
        unsigned p[8];
#pragma unroll
        for (int j = 0; j < 8; ++j) {
            int ii = i0 + j;
            p[j] = epack[ii < e ? ii : i0];       // slot 0 always valid
        }
        uint4 r[8];
        float n[8];
#pragma unroll
        for (int j = 0; j < 8; ++j) {
            n[j] = (i0 + j < e) ? __uint_as_float(p[j] << 16) : 0.0f;
            r[j] = T4[(size_t)(p[j] >> 16) * 8 + l];
        }
#pragma unroll
        for (int j = 0; j < 8; ++j) {
            float f[8];
            bfx8(r[j], f);
#pragma unroll
            for (int k = 0; k < 8; ++k) acc[k] = fmaf(n[j], f[k], acc[k]);
        }
    }
#pragma unroll
    for (int k = 0; k < 8; ++k) acc[k] = fmaxf(acc[k], 0.f);
}

// fused: A = relu(agg(Tb)+b) (32 nodes -> LDS), then Tbn = A @ W (64x64).
// Ws staged bf16 -> 16.9 KB LDS -> 8 blocks/CU (wave-capped, 100% occupancy).
__global__ void __launch_bounds__(256) gmm64(const unsigned short* __restrict__ Tb,
                                             const float* __restrict__ bias,
                                             const float* __restrict__ dinv,
                                             const int* __restrict__ row_ptr,
                                             const unsigned* __restrict__ epack,
                                             const float* __restrict__ W,
                                             unsigned short* __restrict__ Tbn) {
    __shared__ float As[32 * 68];
    __shared__ unsigned short Wsh[64 * 64];
    const int tid = threadIdx.x;
    const int node0 = blockIdx.x * 32;

    // stage W as bf16 (8.2 KB)
#pragma unroll
    for (int p = 0; p < 4; ++p) {
        int idx = tid + p * 256;
        int r = idx >> 4, c4 = idx & 15;
        float4 v = *reinterpret_cast<const float4*>(W + (size_t)r * 64 + c4 * 4);
        uint2 pk;
        pk.x = pack2bf(v.x, v.y);
        pk.y = pack2bf(v.z, v.w);
        *reinterpret_cast<uint2*>(&Wsh[r * 64 + c4 * 4]) = pk;
    }

    // gather 32 nodes -> As
    const int l = tid & 7;
    const int slot = tid >> 3;
    float acc[8];
    gather_node(reinterpret_cast<const uint4*>(Tb), bias, dinv, row_ptr, epack,
                node0 + slot, l, acc);
    *reinterpret_cast<float4*>(&As[slot * 68 + l * 8]) =
        make_float4(acc[0], acc[1], acc[2], acc[3]);
    *reinterpret_cast<float4*>(&As[slot * 68 + l * 8 + 4]) =
        make_float4(acc[4], acc[5], acc[6], acc[7]);
    __syncthreads();

    // mm: 2 rows x 4 cols per thread; Wsh unpacked per k
    const int tx = tid & 15;
    const int ty = tid >> 4;
    float4 c0 = make_float4(0.f, 0.f, 0.f, 0.f);
    float4 c1 = make_float4(0.f, 0.f, 0.f, 0.f);
#pragma unroll 16
    for (int k = 0; k < 64; ++k) {
        uint2 wp = *reinterpret_cast<const uint2*>(&Wsh[k * 64 + tx * 4]);
        float4 w;
        w.x = __uint_as_float(wp.x << 16);
        w.y = __uint_as_float(wp.x & 0xffff0000u);
        w.z = __uint_as_float(wp.y << 16);
        w.w = __uint_as_float(wp.y & 0xffff0000u);
        float a0 = As[(ty * 2 + 0) * 68 + k];
        float a1 = As[(ty * 2 + 1) * 68 + k];
        c0 = f4fma(a0, w, c0);
        c1 = f4fma(a1, w, c1);
    }
    uint2 pk;
    pk.x = pack2bf(c0.x, c0.y);
    pk.y = pack2bf(c0.z, c0.w);
    *reinterpret_cast<uint2*>(Tbn + (size_t)(node0 + ty * 2 + 0) * 64 + tx * 4) = pk;
    pk.x = pack2bf(c1.x, c1.y);
    pk.y = pack2bf(c1.z, c1.w);
    *reinterpret_cast<uint2*>(Tbn + (size_t)(node0 + ty * 2 + 1) * 64 + tx * 4) = pk;
}

// fused final: A = relu(agg(Tb)+b) (32 nodes -> LDS), then T8 = A @ W8 (64x2), fp32.
__global__ void __launch_bounds__(256) gmm2(const unsigned short* __restrict__ Tb,
                                            const float* __restrict__ bias,
                                            const float* __restrict__ dinv,
                                            const int* __restrict__ row_ptr,
                                            const unsigned* __restrict__ epack,
                                            const float* __restrict__ W8,
                                            float* __restrict__ T8) {
    __shared__ float As[32 * 68];
    const int tid = threadIdx.x;
    const int node0 = blockIdx.x * 32;
    const int l = tid & 7;
    const int slot = tid >> 3;
    float acc[8];
    gather_node(reinterpret_cast<const uint4*>(Tb), bias, dinv, row_ptr, epack,
                node0 + slot, l, acc);
    *reinterpret_cast<float4*>(&As[slot * 68 + l * 8]) =
        make_float4(acc[0], acc[1], acc[2], acc[3]);
    *reinterpret_cast<float4*>(&As[slot * 68 + l * 8 + 4]) =
        make_float4(acc[4], acc[5], acc[6], acc[7]);
    __syncthreads();
    if (tid < 64) {
        const int nd = tid >> 1, c = tid & 1;
        float s = 0.f;
#pragma unroll 16
        for (int k = 0; k < 64; ++k) s = fmaf(As[nd * 68 + k], W8[k * 2 + c], s);
        T8[(size_t)(node0 + nd) * 2 + c] = s;
    }
}

// wave per node; lane = (edge j 0..31) x (col c 0..1). fp32.
__global__ void __launch_bounds__(256) gather2(const float* __restrict__ T8,
                                               const float* __restrict__ b8,
                                               const float* __restrict__ dinv,
                                               const int* __restrict__ row_ptr,
                                               const unsigned* __restrict__ epack,
                                               float* __restrict__ out) {
    const int lane = threadIdx.x & 63;
    const int c = lane & 1;
    const int j = lane >> 1;  // 0..31
    const int node = blockIdx.x * 4 + (threadIdx.x >> 6);
    const int s = row_ptr[node];
    const int e = row_ptr[node + 1];
    float acc = 0.f;
    for (int i = s + j; i < e; i += 32) {
        unsigned p = epack[i];
        acc += __uint_as_float(p << 16) * T8[(size_t)(p >> 16) * 2 + c];
    }
    acc += __shfl_xor(acc, 2);
    acc += __shfl_xor(acc, 4);
    acc += __shfl_xor(acc, 8);
    acc += __shfl_xor(acc, 16);
    acc += __shfl_xor(acc, 32);
    if (j == 0) {
        const float dv = dinv[node];
        out[(size_t)node * 2 + c] = b8[c] + dv * dv * T8[(size_t)node * 2 + c] + acc;
    }
}

// ---------------- launcher ----------------

extern "C" void kernel_launch(void* const* d_in, const int* in_sizes, int n_in,
                              void* d_out, int out_size, void* d_ws, size_t ws_size,
                              hipStream_t stream) {
    const float* x  = (const float*)d_in[0];
    const int*   ei = (const int*)d_in[1];   // [2, NE]: [0:NE)=row(src), [NE:2NE)=col(dst)
    const float* ea = (const float*)d_in[2];
    const float* W1 = (const float*)d_in[3];
    const float* b1 = (const float*)d_in[4];
    const float* W2 = (const float*)d_in[5];
    const float* b2 = (const float*)d_in[6];
    const float* W3 = (const float*)d_in[7];
    const float* b3 = (const float*)d_in[8];
    const float* W4 = (const float*)d_in[9];
    const float* b4 = (const float*)d_in[10];
    const float* W5 = (const float*)d_in[11];
    const float* b5 = (const float*)d_in[12];
    const float* W8 = (const float*)d_in[13];
    const float* b8 = (const float*)d_in[14];
    float* out = (float*)d_out;

    // workspace layout (~22 MB)
    unsigned short* Tb1 = (unsigned short*)d_ws;           // NN*64 bf16 (8 MB)
    unsigned short* Tb2 = Tb1 + (size_t)NN * 64;           // NN*64 bf16 (8 MB)
    int*   rank   = (int*)Tb2;                             // aliases Tb2 (dead before gmm64 #1)
    unsigned* epack = (unsigned*)(Tb2 + (size_t)NN * 64);  // NE u32 (4 MB)
    unsigned long long* cntdeg = (unsigned long long*)(epack + NE);  // NN ull
    float* dinv   = (float*)(cntdeg + NN);                 // NN
    int*   row_ptr= (int*)(dinv + NN);                     // NN+1
    float* T8     = (float*)(row_ptr + NN + 1);            // NN*2
    int*   blocksum  = (int*)(T8 + (size_t)NN * 2);        // 256
    int*   blockbase = blocksum + 256;                     // 256

    const int* e_row = ei;
    const int* e_col = ei + NE;

    (void)hipMemsetAsync(cntdeg, 0, (size_t)NN * 8, stream);

    deg_count<<<NE / 256, 256, 0, stream>>>(e_col, ea, cntdeg, rank);
    scan1<<<NN / 256, 256, 0, stream>>>(cntdeg, row_ptr, blocksum, dinv);
    scan2<<<1, 256, 0, stream>>>(blocksum, blockbase, row_ptr);
    scan3<<<NN / 256, 256, 0, stream>>>(row_ptr, blockbase);
    // CSR fill (4096 blocks) + layer-1 mm (1024 blocks), interleaved 4:1
    fill_mm<<<5120, 256, 0, stream>>>(e_row, e_col, ea, dinv, row_ptr, rank, epack,
                                      x, W1, Tb1);

    // fused layers: gather(Tb,b)+relu -> LDS -> @W -> Tbn
    gmm64<<<NN / 32, 256, 0, stream>>>(Tb1, b1, dinv, row_ptr, epack, W2, Tb2);
    gmm64<<<NN / 32, 256, 0, stream>>>(Tb2, b2, dinv, row_ptr, epack, W3, Tb1);
    gmm64<<<NN / 32, 256, 0, stream>>>(Tb1, b3, dinv, row_ptr, epack, W4, Tb2);
    gmm64<<<NN / 32, 256, 0, stream>>>(Tb2, b4, dinv, row_ptr, epack, W5, Tb1);
    gmm2<<<NN / 32, 256, 0, stream>>>(Tb1, b5, dinv, row_ptr, epack, W8, T8);
    // final aggregate in 2-dim space
    gather2<<<NN / 4, 256, 0, stream>>>(T8, b8, dinv, row_ptr, epack, out);
}

// Round 16
// 218.726 us; speedup vs baseline: 1.0795x; 1.0795x over previous
//
#include <hip/hip_runtime.h>
#include <hip/hip_bf16.h>
#include <math.h>

#define NN 65536
#define NE 1048576
#define DEG_SCALE 33554432.0f  // 2^25

__device__ inline float4 f4fma(float s, float4 v, float4 a) {
    a.x = fmaf(s, v.x, a.x);
    a.y = fmaf(s, v.y, a.y);
    a.z = fmaf(s, v.z, a.z);
    a.w = fmaf(s, v.w, a.w);
    return a;
}

__device__ inline unsigned pack2bf(float a, float b) {
    __hip_bfloat16 ha = __float2bfloat16(a), hb = __float2bfloat16(b);
    return (unsigned)*reinterpret_cast<unsigned short*>(&ha) |
           ((unsigned)*reinterpret_cast<unsigned short*>(&hb) << 16);
}

__device__ inline unsigned short bf16bits(float a) {
    __hip_bfloat16 h = __float2bfloat16(a);
    return *reinterpret_cast<unsigned short*>(&h);
}

__device__ inline void bfx8(uint4 v, float* f) {  // 8 bf16 -> 8 fp32
    f[0] = __uint_as_float(v.x << 16);
    f[1] = __uint_as_float(v.x & 0xffff0000u);
    f[2] = __uint_as_float(v.y << 16);
    f[3] = __uint_as_float(v.y & 0xffff0000u);
    f[4] = __uint_as_float(v.z << 16);
    f[5] = __uint_as_float(v.z & 0xffff0000u);
    f[6] = __uint_as_float(v.w << 16);
    f[7] = __uint_as_float(v.w & 0xffff0000u);
}

// mm body, fp32 A input: C[64x64](bf16) = A[64 x K](fp32) @ W[K x 64](fp32)
template <int K>
__device__ void mm64_body_bf(const float* __restrict__ A, const float* __restrict__ W,
                             unsigned short* __restrict__ Cb, int node0, int tid) {
    __shared__ float As[64 * 68];
    __shared__ float Ws[64 * 64];
    const int tx = tid & 15;
    const int ty = tid >> 4;
    float4 acc[4];
#pragma unroll
    for (int m = 0; m < 4; ++m) acc[m] = make_float4(0.f, 0.f, 0.f, 0.f);

    for (int kc = 0; kc < K; kc += 64) {
#pragma unroll
        for (int p = 0; p < 4; ++p) {
            int idx = tid + p * 256;
            int r = idx >> 4, c4 = idx & 15;
            float4 v = *reinterpret_cast<const float4*>(A + (size_t)(node0 + r) * K + kc + c4 * 4);
            *reinterpret_cast<float4*>(&As[r * 68 + c4 * 4]) = v;
        }
#pragma unroll
        for (int p = 0; p < 4; ++p) {
            int idx = tid + p * 256;
            int r = idx >> 4, c4 = idx & 15;
            float4 v = *reinterpret_cast<const float4*>(W + (size_t)(kc + r) * 64 + c4 * 4);
            *reinterpret_cast<float4*>(&Ws[r * 64 + c4 * 4]) = v;
        }
        __syncthreads();
#pragma unroll 16
        for (int k = 0; k < 64; ++k) {
            float4 w = *reinterpret_cast<const float4*>(&Ws[k * 64 + tx * 4]);
            float a0 = As[(ty * 4 + 0) * 68 + k];
            float a1 = As[(ty * 4 + 1) * 68 + k];
            float a2 = As[(ty * 4 + 2) * 68 + k];
            float a3 = As[(ty * 4 + 3) * 68 + k];
            acc[0] = f4fma(a0, w, acc[0]);
            acc[1] = f4fma(a1, w, acc[1]);
            acc[2] = f4fma(a2, w, acc[2]);
            acc[3] = f4fma(a3, w, acc[3]);
        }
        __syncthreads();
    }
#pragma unroll
    for (int m = 0; m < 4; ++m) {
        uint2 pk;
        pk.x = pack2bf(acc[m].x, acc[m].y);
        pk.y = pack2bf(acc[m].z, acc[m].w);
        *reinterpret_cast<uint2*>(Cb + (size_t)(node0 + ty * 4 + m) * 64 + tx * 4) = pk;
    }
}

// ---------------- setup (merged with layer-1 mm) ----------------

__global__ void __launch_bounds__(256) setup_mm(const int* __restrict__ col,
                                                const float* __restrict__ ew,
                                                unsigned long long* __restrict__ cntdeg,
                                                int* __restrict__ rank,
                                                const float* __restrict__ x,
                                                const float* __restrict__ W1,
                                                unsigned short* __restrict__ Tb) {
    const int bid = blockIdx.x;
    const int tid = threadIdx.x;
    if (bid % 5 == 0) {
        mm64_body_bf<128>(x, W1, Tb, (bid / 5) * 64, tid);
    } else {
        int e = (bid - bid / 5 - 1) * 256 + tid;
        if (e < NE) {
            int c = col[e];
            unsigned long long p =
                (1ull << 32) | (unsigned long long)__float2uint_rn(ew[e] * DEG_SCALE);
            unsigned long long old = atomicAdd(&cntdeg[c], p);
            rank[e] = (int)(old >> 32);
        }
    }
}

// phase 1: per-block (256 nodes) exclusive scan of counts; emit block total + dinv.
__global__ void __launch_bounds__(256) scan1(const unsigned long long* __restrict__ cntdeg,
                                             int* __restrict__ row_ptr,
                                             int* __restrict__ blocksum,
                                             float* __restrict__ dinv) {
    __shared__ int ls[256];
    const int t = threadIdx.x;
    const int i = blockIdx.x * 256 + t;
    unsigned long long v = cntdeg[i];
    const int c = (int)(v >> 32);
    float deg = (float)(unsigned)(v & 0xffffffffull) * (1.0f / DEG_SCALE) + 1.0f;
    dinv[i] = 1.0f / sqrtf(deg);
    ls[t] = c;
    __syncthreads();
#pragma unroll
    for (int off = 1; off < 256; off <<= 1) {
        int u = (t >= off) ? ls[t - off] : 0;
        __syncthreads();
        ls[t] += u;
        __syncthreads();
    }
    row_ptr[i] = ls[t] - c;  // exclusive
    if (t == 255) blocksum[blockIdx.x] = ls[255];
}

__global__ void __launch_bounds__(256) scan2(const int* __restrict__ blocksum,
                                             int* __restrict__ blockbase,
                                             int* __restrict__ row_ptr) {
    __shared__ int ls[256];
    const int t = threadIdx.x;
    const int c = blocksum[t];
    ls[t] = c;
    __syncthreads();
#pragma unroll
    for (int off = 1; off < 256; off <<= 1) {
        int u = (t >= off) ? ls[t - off] : 0;
        __syncthreads();
        ls[t] += u;
        __syncthreads();
    }
    blockbase[t] = ls[t] - c;
    if (t == 255) row_ptr[NN] = ls[255];
}

__global__ void __launch_bounds__(256) scan3(int* __restrict__ row_ptr,
                                             const int* __restrict__ blockbase) {
    const int i = blockIdx.x * 256 + threadIdx.x;
    row_ptr[i] += blockbase[blockIdx.x];
}

// atomic-free CSR fill; 4-byte edge record: (src << 16) | bf16(nrm).
__global__ void __launch_bounds__(256) fill_kernel(const int* __restrict__ row,
                                                   const int* __restrict__ col,
                                                   const float* __restrict__ ew,
                                                   const float* __restrict__ dinv,
                                                   const int* __restrict__ row_ptr,
                                                   const int* __restrict__ rank,
                                                   unsigned* __restrict__ epack) {
    int e = blockIdx.x * 256 + threadIdx.x;
    if (e < NE) {
        int c = col[e], r = row[e];
        int idx = row_ptr[c] + rank[e];
        float nrm = dinv[r] * ew[e] * dinv[c];
        epack[idx] = ((unsigned)r << 16) | (unsigned)bf16bits(nrm);
    }
}

// ---------------- fused layer kernels ----------------

// gather phase: 8 lanes per node, 8-wide clamped-predicated loop, fp32 acc.
// edge record: src = p>>16, nrm = as_float(p<<16).
__device__ inline void gather_node(const uint4* __restrict__ T4,
                                   const float* __restrict__ bias,
                                   const float* __restrict__ dinv,
                                   const int* __restrict__ row_ptr,
                                   const unsigned* __restrict__ epack,
                                   int node, int l, float* acc) {
    const float dv = dinv[node];
    {
        float ts[8];
        bfx8(T4[(size_t)node * 8 + l], ts);
        float4 bA = *reinterpret_cast<const float4*>(bias + l * 8);
        float4 bB = *reinterpret_cast<const float4*>(bias + l * 8 + 4);
        acc[0] = bA.x + dv * dv * ts[0];
        acc[1] = bA.y + dv * dv * ts[1];
        acc[2] = bA.z + dv * dv * ts[2];
        acc[3] = bA.w + dv * dv * ts[3];
        acc[4] = bB.x + dv * dv * ts[4];
        acc[5] = bB.y + dv * dv * ts[5];
        acc[6] = bB.z + dv * dv * ts[6];
        acc[7] = bB.w + dv * dv * ts[7];
    }
    const int s = row_ptr[node];
    const int e = row_ptr[node + 1];
    for (int i0 = s; i0 < e; i0 += 8) {
        unsigned p[8];
#pragma unroll
        for (int j = 0; j < 8; ++j) {
            int ii = i0 + j;
            p[j] = epack[ii < e ? ii : i0];       // slot 0 always valid
        }
        uint4 r[8];
        float n[8];
#pragma unroll
        for (int j = 0; j < 8; ++j) {
            n[j] = (i0 + j < e) ? __uint_as_float(p[j] << 16) : 0.0f;
            r[j] = T4[(size_t)(p[j] >> 16) * 8 + l];
        }
#pragma unroll
        for (int j = 0; j < 8; ++j) {
            float f[8];
            bfx8(r[j], f);
#pragma unroll
            for (int k = 0; k < 8; ++k) acc[k] = fmaf(n[j], f[k], acc[k]);
        }
    }
#pragma unroll
    for (int k = 0; k < 8; ++k) acc[k] = fmaxf(acc[k], 0.f);
}

// fused: A = relu(agg(Tb)+b) (32 nodes -> LDS), then Tbn = A @ W (64x64). W fp32 in LDS.
__global__ void __launch_bounds__(256) gmm64(const unsigned short* __restrict__ Tb,
                                             const float* __restrict__ bias,
                                             const float* __restrict__ dinv,
                                             const int* __restrict__ row_ptr,
                                             const unsigned* __restrict__ epack,
                                             const float* __restrict__ W,
                                             unsigned short* __restrict__ Tbn) {
    __shared__ float As[32 * 68];
    __shared__ float Ws[64 * 64];
    const int tid = threadIdx.x;
    const int node0 = blockIdx.x * 32;

    // stage W (16 KB)
#pragma unroll
    for (int p = 0; p < 4; ++p) {
        int idx = tid + p * 256;
        int r = idx >> 4, c4 = idx & 15;
        *reinterpret_cast<float4*>(&Ws[r * 64 + c4 * 4]) =
            *reinterpret_cast<const float4*>(W + (size_t)r * 64 + c4 * 4);
    }

    // gather 32 nodes -> As
    const int l = tid & 7;
    const int slot = tid >> 3;
    float acc[8];
    gather_node(reinterpret_cast<const uint4*>(Tb), bias, dinv, row_ptr, epack,
                node0 + slot, l, acc);
    *reinterpret_cast<float4*>(&As[slot * 68 + l * 8]) =
        make_float4(acc[0], acc[1], acc[2], acc[3]);
    *reinterpret_cast<float4*>(&As[slot * 68 + l * 8 + 4]) =
        make_float4(acc[4], acc[5], acc[6], acc[7]);
    __syncthreads();

    // mm: 2 rows x 4 cols per thread
    const int tx = tid & 15;
    const int ty = tid >> 4;
    float4 c0 = make_float4(0.f, 0.f, 0.f, 0.f);
    float4 c1 = make_float4(0.f, 0.f, 0.f, 0.f);
#pragma unroll 16
    for (int k = 0; k < 64; ++k) {
        float4 w = *reinterpret_cast<const float4*>(&Ws[k * 64 + tx * 4]);
        float a0 = As[(ty * 2 + 0) * 68 + k];
        float a1 = As[(ty * 2 + 1) * 68 + k];
        c0 = f4fma(a0, w, c0);
        c1 = f4fma(a1, w, c1);
    }
    uint2 pk;
    pk.x = pack2bf(c0.x, c0.y);
    pk.y = pack2bf(c0.z, c0.w);
    *reinterpret_cast<uint2*>(Tbn + (size_t)(node0 + ty * 2 + 0) * 64 + tx * 4) = pk;
    pk.x = pack2bf(c1.x, c1.y);
    pk.y = pack2bf(c1.z, c1.w);
    *reinterpret_cast<uint2*>(Tbn + (size_t)(node0 + ty * 2 + 1) * 64 + tx * 4) = pk;
}

// fused final: A = relu(agg(Tb)+b) (32 nodes -> LDS), then T8 = A @ W8 (64x2), fp32.
__global__ void __launch_bounds__(256) gmm2(const unsigned short* __restrict__ Tb,
                                            const float* __restrict__ bias,
                                            const float* __restrict__ dinv,
                                            const int* __restrict__ row_ptr,
                                            const unsigned* __restrict__ epack,
                                            const float* __restrict__ W8,
                                            float* __restrict__ T8) {
    __shared__ float As[32 * 68];
    const int tid = threadIdx.x;
    const int node0 = blockIdx.x * 32;
    const int l = tid & 7;
    const int slot = tid >> 3;
    float acc[8];
    gather_node(reinterpret_cast<const uint4*>(Tb), bias, dinv, row_ptr, epack,
                node0 + slot, l, acc);
    *reinterpret_cast<float4*>(&As[slot * 68 + l * 8]) =
        make_float4(acc[0], acc[1], acc[2], acc[3]);
    *reinterpret_cast<float4*>(&As[slot * 68 + l * 8 + 4]) =
        make_float4(acc[4], acc[5], acc[6], acc[7]);
    __syncthreads();
    if (tid < 64) {
        const int nd = tid >> 1, c = tid & 1;
        float s = 0.f;
#pragma unroll 16
        for (int k = 0; k < 64; ++k) s = fmaf(As[nd * 68 + k], W8[k * 2 + c], s);
        T8[(size_t)(node0 + nd) * 2 + c] = s;
    }
}

// wave per node; lane = (edge j 0..31) x (col c 0..1). fp32.
__global__ void __launch_bounds__(256) gather2(const float* __restrict__ T8,
                                               const float* __restrict__ b8,
                                               const float* __restrict__ dinv,
                                               const int* __restrict__ row_ptr,
                                               const unsigned* __restrict__ epack,
                                               float* __restrict__ out) {
    const int lane = threadIdx.x & 63;
    const int c = lane & 1;
    const int j = lane >> 1;  // 0..31
    const int node = blockIdx.x * 4 + (threadIdx.x >> 6);
    const int s = row_ptr[node];
    const int e = row_ptr[node + 1];
    float acc = 0.f;
    for (int i = s + j; i < e; i += 32) {
        unsigned p = epack[i];
        acc += __uint_as_float(p << 16) * T8[(size_t)(p >> 16) * 2 + c];
    }
    acc += __shfl_xor(acc, 2);
    acc += __shfl_xor(acc, 4);
    acc += __shfl_xor(acc, 8);
    acc += __shfl_xor(acc, 16);
    acc += __shfl_xor(acc, 32);
    if (j == 0) {
        const float dv = dinv[node];
        out[(size_t)node * 2 + c] = b8[c] + dv * dv * T8[(size_t)node * 2 + c] + acc;
    }
}

// ---------------- launcher ----------------

extern "C" void kernel_launch(void* const* d_in, const int* in_sizes, int n_in,
                              void* d_out, int out_size, void* d_ws, size_t ws_size,
                              hipStream_t stream) {
    const float* x  = (const float*)d_in[0];
    const int*   ei = (const int*)d_in[1];   // [2, NE]: [0:NE)=row(src), [NE:2NE)=col(dst)
    const float* ea = (const float*)d_in[2];
    const float* W1 = (const float*)d_in[3];
    const float* b1 = (const float*)d_in[4];
    const float* W2 = (const float*)d_in[5];
    const float* b2 = (const float*)d_in[6];
    const float* W3 = (const float*)d_in[7];
    const float* b3 = (const float*)d_in[8];
    const float* W4 = (const float*)d_in[9];
    const float* b4 = (const float*)d_in[10];
    const float* W5 = (const float*)d_in[11];
    const float* b5 = (const float*)d_in[12];
    const float* W8 = (const float*)d_in[13];
    const float* b8 = (const float*)d_in[14];
    float* out = (float*)d_out;

    // workspace layout (~22 MB)
    unsigned short* Tb1 = (unsigned short*)d_ws;           // NN*64 bf16 (8 MB)
    unsigned short* Tb2 = Tb1 + (size_t)NN * 64;           // NN*64 bf16 (8 MB)
    int*   rank   = (int*)Tb2;                             // aliases Tb2 (dead before gmm64 #1)
    unsigned* epack = (unsigned*)(Tb2 + (size_t)NN * 64);  // NE u32 (4 MB)
    unsigned long long* cntdeg = (unsigned long long*)(epack + NE);  // NN ull
    float* dinv   = (float*)(cntdeg + NN);                 // NN
    int*   row_ptr= (int*)(dinv + NN);                     // NN+1
    float* T8     = (float*)(row_ptr + NN + 1);            // NN*2
    int*   blocksum  = (int*)(T8 + (size_t)NN * 2);        // 256
    int*   blockbase = blocksum + 256;                     // 256

    const int* e_row = ei;
    const int* e_col = ei + NE;

    (void)hipMemsetAsync(cntdeg, 0, (size_t)NN * 8, stream);

    // deg_count (4096 blocks) + layer-1 mm (1024 blocks), interleaved 4:1
    setup_mm<<<5120, 256, 0, stream>>>(e_col, ea, cntdeg, rank, x, W1, Tb1);
    scan1<<<NN / 256, 256, 0, stream>>>(cntdeg, row_ptr, blocksum, dinv);
    scan2<<<1, 256, 0, stream>>>(blocksum, blockbase, row_ptr);
    scan3<<<NN / 256, 256, 0, stream>>>(row_ptr, blockbase);
    fill_kernel<<<NE / 256, 256, 0, stream>>>(e_row, e_col, ea, dinv, row_ptr, rank, epack);

    // fused layers: gather(Tb,b)+relu -> LDS -> @W -> Tbn
    gmm64<<<NN / 32, 256, 0, stream>>>(Tb1, b1, dinv, row_ptr, epack, W2, Tb2);
    gmm64<<<NN / 32, 256, 0, stream>>>(Tb2, b2, dinv, row_ptr, epack, W3, Tb1);
    gmm64<<<NN / 32, 256, 0, stream>>>(Tb1, b3, dinv, row_ptr, epack, W4, Tb2);
    gmm64<<<NN / 32, 256, 0, stream>>>(Tb2, b4, dinv, row_ptr, epack, W5, Tb1);
    gmm2<<<NN / 32, 256, 0, stream>>>(Tb1, b5, dinv, row_ptr, epack, W8, T8);
    // final aggregate in 2-dim space
    gather2<<<NN / 4, 256, 0, stream>>>(T8, b8, dinv, row_ptr, epack, out);
}